// Round 15
// baseline (151.952 us; speedup 1.0000x reference)
//
#include <hip/hip_runtime.h>
#include <cstdint>

#define Bv  2
#define Tv  2048
#define Dv  1024
#define Hv  16
#define DHv 64
#define Pv  512
#define Lv  2560   // P + T
#define NT  (Lv / 64)   // 40 key tiles

typedef __attribute__((ext_vector_type(8))) short sh8;   // 8 bf16 MFMA frag
typedef __attribute__((ext_vector_type(4))) short sh4;
typedef __attribute__((ext_vector_type(4))) float f4;
typedef __attribute__((ext_vector_type(4))) unsigned int u4v;

#define MFMA(a,b,c) __builtin_amdgcn_mfma_f32_16x16x32_bf16(a,b,c,0,0,0)

__device__ __forceinline__ unsigned short bf16_rn(float f) {
    unsigned int u = __builtin_bit_cast(unsigned int, f);
    u += 0x7FFFu + ((u >> 16) & 1u);          // RTNE
    return (unsigned short)(u >> 16);
}
__device__ __forceinline__ float bf16_f(unsigned short h) {
    unsigned int u = ((unsigned int)h) << 16;
    return __builtin_bit_cast(float, u);
}
__device__ __forceinline__ unsigned int fbits(float f) {
    return __builtin_bit_cast(unsigned int, f);
}

// async global->LDS, 16B per lane; LDS dest = wave-uniform base + lane*16
__device__ __forceinline__ void gload16(const unsigned short* g, unsigned short* l) {
    __builtin_amdgcn_global_load_lds(
        (const __attribute__((address_space(1))) unsigned int*)(g),
        (__attribute__((address_space(3))) unsigned int*)(l),
        16, 0, 0);
}

// exp2 + truncate-pack two QK accumulators (8 P values) into one bf16 B-frag.
__device__ __forceinline__ sh8 packP(const f4 a, const f4 b) {
    float e0 = __builtin_amdgcn_exp2f(a[0]), e1 = __builtin_amdgcn_exp2f(a[1]);
    float e2 = __builtin_amdgcn_exp2f(a[2]), e3 = __builtin_amdgcn_exp2f(a[3]);
    float f0 = __builtin_amdgcn_exp2f(b[0]), f1 = __builtin_amdgcn_exp2f(b[1]);
    float f2 = __builtin_amdgcn_exp2f(b[2]), f3 = __builtin_amdgcn_exp2f(b[3]);
    u4v d;
    d[0] = __builtin_amdgcn_perm(fbits(e1), fbits(e0), 0x07060302u);
    d[1] = __builtin_amdgcn_perm(fbits(e3), fbits(e2), 0x07060302u);
    d[2] = __builtin_amdgcn_perm(fbits(f1), fbits(f0), 0x07060302u);
    d[3] = __builtin_amdgcn_perm(fbits(f3), fbits(f2), 0x07060302u);
    return __builtin_bit_cast(sh8, d);
}

// ---------------------------------------------------------------------------
// Prep (merged): blocks [0,9216) = fp32->bf16 conversions (x,Wq,Wk,Wv,pk,Wo);
// blocks [9216,9472) = pv transpose to [B,H,DH,P'] with tau-permuted keys.
// ---------------------------------------------------------------------------
__global__ __launch_bounds__(256) void prep_all(
    const float* __restrict__ x,  const float* __restrict__ Wq,
    const float* __restrict__ Wk, const float* __restrict__ Wv,
    const float* __restrict__ pk, const float* __restrict__ Wo,
    const float* __restrict__ pv,
    unsigned short* __restrict__ xb,  unsigned short* __restrict__ wqb,
    unsigned short* __restrict__ wkb, unsigned short* __restrict__ wvb,
    unsigned short* __restrict__ pkb, unsigned short* __restrict__ woh,
    unsigned short* __restrict__ pvtb)
{
    __shared__ unsigned short Tls[64][66];
    const int blk = blockIdx.x;
    const int tid = threadIdx.x;
    if (blk < 9216) {
        int i = blk * 256 + tid;              // float4 index, total 2359296
        const float* src; unsigned short* dst; int off;
        if      (i < 1048576) { src = x;  dst = xb;  off = i; }
        else if (i < 1310720) { src = Wq; dst = wqb; off = i - 1048576; }
        else if (i < 1572864) { src = Wk; dst = wkb; off = i - 1310720; }
        else if (i < 1835008) { src = Wv; dst = wvb; off = i - 1572864; }
        else if (i < 2097152) { src = pk; dst = pkb; off = i - 1835008; }
        else                  { src = Wo; dst = woh; off = i - 2097152; }
        float4 v = reinterpret_cast<const float4*>(src)[off];
        sh4 h;
        h[0] = (short)bf16_rn(v.x); h[1] = (short)bf16_rn(v.y);
        h[2] = (short)bf16_rn(v.z); h[3] = (short)bf16_rn(v.w);
        reinterpret_cast<sh4*>(dst)[off] = h;
    } else {
        const int bb = blk - 9216;            // 0..255
        const int bh = bb >> 3, pt = bb & 7;
        #pragma unroll
        for (int i = 0; i < 4; i++) {
            int id = i * 256 + tid;
            int p = id >> 4, c4 = (id & 15) << 2;
            float4 v = *reinterpret_cast<const float4*>(
                &pv[((size_t)bh * Pv + pt * 64 + p) * DHv + c4]);
            Tls[c4+0][p] = bf16_rn(v.x);
            Tls[c4+1][p] = bf16_rn(v.y);
            Tls[c4+2][p] = bf16_rn(v.z);
            Tls[c4+3][p] = bf16_rn(v.w);
        }
        __syncthreads();
        #pragma unroll
        for (int i = 0; i < 2; i++) {
            int id = i * 256 + tid;
            int d = id >> 3, u = id & 7;      // dh row, 8-key run index
            sh4 lo, hi;
            #pragma unroll
            for (int j = 0; j < 4; j++) {
                lo[j] = (short)Tls[d][u * 8 + j];
                hi[j] = (short)Tls[d][u * 8 + 4 + j];
            }
            int p0 = ((u >> 2) & 1) * 32 + (u & 1) * 16 + ((u >> 1) & 1) * 4;
            size_t base = ((size_t)bh * DHv + d) * Pv + pt * 64;
            *reinterpret_cast<sh4*>(&pvtb[base + p0])     = lo;
            *reinterpret_cast<sh4*>(&pvtb[base + p0 + 8]) = hi;
        }
    }
}

// ---------------------------------------------------------------------------
// Kernel 1: QKV projection, pipelined (2-buffer, counted vmcnt(8)), main loop
// UNROLLED x2 so buffer indices are literals -> LDS addresses constant-fold.
// Q pre-scaled by 0.125*log2(e); V^T stored tau-permuted per 64-tile.
// ---------------------------------------------------------------------------
__global__ __launch_bounds__(256) void qkv_gemm(
    const unsigned short* __restrict__ xb,
    const unsigned short* __restrict__ wqb, const unsigned short* __restrict__ wkb,
    const unsigned short* __restrict__ wvb,
    unsigned short* __restrict__ qb, unsigned short* __restrict__ kb,
    unsigned short* __restrict__ vtb)
{
    __shared__ __align__(16) unsigned short As[2][128 * 64], Bs[2][128 * 64];
    const int tid = threadIdx.x;
    const int lane = tid & 63, w = tid >> 6;
    const int g = lane >> 4, tx = lane & 15;
    const int wr = w >> 1, wc = w & 1;
    const int m0 = blockIdx.x * 128, n0 = blockIdx.y * 128;
    const int z = blockIdx.z;
    const unsigned short* Wb = (z == 0) ? wqb : (z == 1) ? wkb : wvb;
    const int srow = lane >> 3, scol = lane & 7;

    f4 acc[4][4] = {};

    auto stage = [&](int buf, int step) {      // 8 gload16 per wave
        int k0 = step * 64;
        #pragma unroll
        for (int c = 0; c < 4; c++) {
            int row = w * 32 + c * 8 + srow;
            int su = (scol ^ (row & 7)) << 3;
            gload16(&xb[(size_t)(m0 + row) * Dv + k0 + su], &As[buf][(w * 32 + c * 8) * 64]);
            gload16(&Wb[(size_t)(n0 + row) * Dv + k0 + su], &Bs[buf][(w * 32 + c * 8) * 64]);
        }
    };
    auto compute = [&](int buf) {
        #pragma unroll
        for (int ks = 0; ks < 2; ks++) {
            sh8 fa[4], fb[4];
            #pragma unroll
            for (int mi = 0; mi < 4; mi++) {
                int r = wr * 64 + mi * 16 + tx;
                fa[mi] = *reinterpret_cast<const sh8*>(
                    &As[buf][(r * 64 + ks * 32 + g * 8) ^ ((r & 7) << 3)]);
            }
            #pragma unroll
            for (int ni = 0; ni < 4; ni++) {
                int r = wc * 64 + ni * 16 + tx;
                fb[ni] = *reinterpret_cast<const sh8*>(
                    &Bs[buf][(r * 64 + ks * 32 + g * 8) ^ ((r & 7) << 3)]);
            }
            if (z < 2) {
                #pragma unroll
                for (int mi = 0; mi < 4; mi++)
                    #pragma unroll
                    for (int ni = 0; ni < 4; ni++)
                        acc[mi][ni] = MFMA(fb[ni], fa[mi], acc[mi][ni]);   // C: row=n, col=m
            } else {
                #pragma unroll
                for (int mi = 0; mi < 4; mi++)
                    #pragma unroll
                    for (int ni = 0; ni < 4; ni++)
                        acc[mi][ni] = MFMA(fa[mi], fb[ni], acc[mi][ni]);   // C: row=m, col=n
            }
        }
    };
    auto step = [&](int buf, int t) {          // literal buf -> static LDS addrs
        if (t < 15) asm volatile("s_waitcnt vmcnt(8)" ::: "memory");
        else        asm volatile("s_waitcnt vmcnt(0)" ::: "memory");
        __builtin_amdgcn_s_barrier();
        __builtin_amdgcn_sched_barrier(0);
        compute(buf);
        __builtin_amdgcn_sched_barrier(0);
        __builtin_amdgcn_s_barrier();
        if (t + 2 < 16) stage(buf, t + 2);
    };

    stage(0, 0); stage(1, 1);                  // 16 loads in flight
    #pragma unroll 1
    for (int tt = 0; tt < 16; tt += 2) { step(0, tt); step(1, tt + 1); }

    if (z < 2) {
        unsigned short* ob = (z == 0) ? qb : kb;
        const float sc = (z == 0) ? 0.1803368801f : 1.0f;   // 0.125*log2(e) into Q
        #pragma unroll
        for (int mi = 0; mi < 4; mi++)
            #pragma unroll
            for (int ni = 0; ni < 4; ni++) {
                int m = m0 + wr * 64 + mi * 16 + tx;          // col of C = x row
                int n = n0 + wc * 64 + ni * 16 + g * 4;       // row of C = W row (base)
                sh4 pkd;
                #pragma unroll
                for (int i = 0; i < 4; i++) pkd[i] = (short)bf16_rn(acc[mi][ni][i] * sc);
                *reinterpret_cast<sh4*>(&ob[(size_t)m * Dv + n]) = pkd;
            }
    } else {
        const int tb0 = ((m0 + wr * 64) & (Tv - 1));          // 64-aligned t-block
        const int b   = (m0 + wr * 64) >> 11;
        #pragma unroll
        for (int mi = 0; mi < 4; mi++)
            #pragma unroll
            for (int ni = 0; ni < 4; ni++) {
                // key = mi*16 + g*4 + i  ->  tau-slot = 32*(mi>>1) + 8g + 4*(mi&1) + i
                int t = tb0 + ((mi & 2) << 4) + (g << 3) + ((mi & 1) << 2);
                int n = n0 + wc * 64 + ni * 16 + tx;          // col of C = W row
                int h = n >> 6, dh = n & 63;
                sh4 pkd;
                #pragma unroll
                for (int i = 0; i < 4; i++) pkd[i] = (short)bf16_rn(acc[mi][ni][i]);
                *reinterpret_cast<sh4*>(&vtb[(((size_t)(b * Hv + h)) * DHv + dh) * Tv + t]) = pkd;
            }
    }
}

// ---------------------------------------------------------------------------
// Kernel 2: flash attention.  KEY-SPLIT + 3-buffer single-barrier pipeline,
// main loop UNROLLED x3 so all LDS buffer indices are literals (static ds
// addressing -- runtime cur was costing ~16 VALU addr ops/tile).  Compute
// reverted to round-12 interleaved form (setprio clustering regressed).
// tau key-relabel keeps P in registers; no-max softmax; l via ones-MFMA.
// ---------------------------------------------------------------------------
__global__ __launch_bounds__(256) void flash_mfma(
    const unsigned short* __restrict__ qbuf, const unsigned short* __restrict__ kb,
    const unsigned short* __restrict__ vtb,
    const unsigned short* __restrict__ pkb, const unsigned short* __restrict__ pvtb,
    unsigned short* __restrict__ yh)
{
    __shared__ __align__(16) unsigned short Ks[3][64 * 64], Vs[3][64 * 64];
    __shared__ float olex[2][4][64];
    const int tid = threadIdx.x;
    const int lane = tid & 63, w = tid >> 6;       // 4 waves
    const int kw = w & 1, qw = w >> 1;             // key-half, q-half
    const int g = lane >> 4, tx = lane & 15;
    // XCD swizzle: 512 blocks, 8 XCDs, chunk=64 => 4 bh per XCD
    const int pblk = blockIdx.x;
    const int L = (pblk & 7) * 64 + (pblk >> 3);
    const int qt = L & 15;                 // 16 q-tiles of 128 rows
    const int bh = L >> 4;
    const int b = bh >> 4, h = bh & 15;
    const int srow = lane >> 3, scol = lane & 7;

    // Q frags: 4 groups x 2 dh-halves (MFMA B-operand, pre-scaled)
    sh8 qf[4][2];
    #pragma unroll
    for (int qg = 0; qg < 4; qg++) {
        size_t base = ((size_t)(b * Tv) + qt * 128 + qw * 64 + qg * 16 + tx) * Dv + h * 64;
        qf[qg][0] = *reinterpret_cast<const sh8*>(&qbuf[base + g * 8]);
        qf[qg][1] = *reinterpret_cast<const sh8*>(&qbuf[base + 32 + g * 8]);
    }

    f4 o[4][4] = {};          // [q-group][dh-frag], partial over this wave's keys
    f4 ol[4] = {};            // ones-colsum accumulators (partial l per group)
    sh8 onesf;
    #pragma unroll
    for (int j = 0; j < 8; j++) onesf[j] = (short)0x3F80;   // bf16 1.0

    // staging pointers (wave stages rows w*16..+15 of both K and V tiles)
    const int r0 = w * 16 + srow, r1 = r0 + 8;
    const int su0 = (scol ^ (r0 & 7)) << 3;
    const int su1 = (scol ^ (r1 & 7)) << 3;
    const unsigned short* ka0 = &pkb[((size_t)bh * Pv + r0) * DHv + su0];
    const unsigned short* ka1 = &pkb[((size_t)bh * Pv + r1) * DHv + su1];
    const unsigned short* va0 = &pvtb[((size_t)bh * DHv + r0) * Pv + su0];
    const unsigned short* va1 = &pvtb[((size_t)bh * DHv + r1) * Pv + su1];

    auto stage = [&](int buf) {            // 4 gload16 per wave per tile
        gload16(ka0, &Ks[buf][(w * 16    ) * 64]);
        gload16(ka1, &Ks[buf][(w * 16 + 8) * 64]);
        gload16(va0, &Vs[buf][(w * 16    ) * 64]);
        gload16(va1, &Vs[buf][(w * 16 + 8) * 64]);
    };
    auto advance = [&](int nt) {           // nt = tile just staged
        if (nt == 7) {                     // switch prefix -> computed arrays
            ka0 = &kb[((size_t)(b * Tv) + r0) * Dv + h * 64 + su0];
            ka1 = &kb[((size_t)(b * Tv) + r1) * Dv + h * 64 + su1];
            va0 = &vtb[((size_t)bh * DHv + r0) * Tv + su0];
            va1 = &vtb[((size_t)bh * DHv + r1) * Tv + su1];
        } else if (nt < 7) { ka0 += 64 * DHv; ka1 += 64 * DHv; va0 += 64; va1 += 64; }
        else               { ka0 += 64 * Dv;  ka1 += 64 * Dv;  va0 += 64; va1 += 64; }
    };

    auto compute = [&](int cur) {          // literal cur -> static LDS addrs
        sh8 kf[2][2], vf[4];
        #pragma unroll
        for (int nf = 0; nf < 2; nf++) {
            int rk = 32 * kw + nf * 16 + tx;
            kf[nf][0] = *reinterpret_cast<const sh8*>(
                &Ks[cur][(rk * 64 + g * 8) ^ ((rk & 7) << 3)]);
            kf[nf][1] = *reinterpret_cast<const sh8*>(
                &Ks[cur][(rk * 64 + 32 + g * 8) ^ ((rk & 7) << 3)]);
        }
        #pragma unroll
        for (int nf = 0; nf < 4; nf++) {
            int rv = nf * 16 + tx;
            vf[nf] = *reinterpret_cast<const sh8*>(
                &Vs[cur][(rv * 64 + 32 * kw + g * 8) ^ ((rv & 7) << 3)]);
        }
        #pragma unroll
        for (int qg = 0; qg < 4; qg++) {
            f4 sa = {}, sb = {};
            sa = MFMA(kf[0][0], qf[qg][0], sa); sa = MFMA(kf[0][1], qf[qg][1], sa);
            sb = MFMA(kf[1][0], qf[qg][0], sb); sb = MFMA(kf[1][1], qf[qg][1], sb);
            sh8 pf = packP(sa, sb);            // tau-slots 32kw + 8g + 4nf' + i
            #pragma unroll
            for (int nf = 0; nf < 4; nf++)
                o[qg][nf] = MFMA(vf[nf], pf, o[qg][nf]);
            ol[qg] = MFMA(onesf, pf, ol[qg]);
        }
    };
    auto body = [&](int curb, int stgb, int t) {
        asm volatile("s_waitcnt vmcnt(4)" ::: "memory");   // tile t landed
        __builtin_amdgcn_s_barrier();
        __builtin_amdgcn_sched_barrier(0);
        stage(stgb); advance(t + 2);       // overwrite target computed at t-1
        compute(curb);
        __builtin_amdgcn_sched_barrier(0);
    };

    stage(0); advance(0);
    stage(1); advance(1);                  // 8 loads in flight

    #pragma unroll 1
    for (int tt = 0; tt < 36; tt += 3) {   // 12 trips x 3 tiles, literal bufs
        body(0, 2, tt); body(1, 0, tt + 1); body(2, 1, tt + 2);
    }
    body(0, 2, 36); body(1, 0, 37);
    asm volatile("s_waitcnt vmcnt(4)" ::: "memory");       // tile 38 landed
    __builtin_amdgcn_s_barrier();
    __builtin_amdgcn_sched_barrier(0);
    compute(2);
    __builtin_amdgcn_sched_barrier(0);
    asm volatile("s_waitcnt vmcnt(0)" ::: "memory");       // tile 39 landed
    __builtin_amdgcn_s_barrier();
    __builtin_amdgcn_sched_barrier(0);
    compute(0);

    // cross-wave (kw) reduction: kw=1 writes partials to dead Ks/Vs, kw=0 adds
    float* ex = qw ? reinterpret_cast<float*>(Vs) : reinterpret_cast<float*>(Ks);
    if (kw) {
        #pragma unroll
        for (int qg = 0; qg < 4; qg++) {
            #pragma unroll
            for (int nf = 0; nf < 4; nf++)
                *reinterpret_cast<f4*>(&ex[((qg * 4 + nf) * 64 + lane) * 4]) = o[qg][nf];
            olex[qw][qg][lane] = ol[qg][0];
        }
    }
    __syncthreads();
    if (!kw) {
        #pragma unroll
        for (int qg = 0; qg < 4; qg++) {
            float l = ol[qg][0] + olex[qw][qg][lane];
            float inv = 1.0f / l;
            size_t ybase = ((size_t)(b * Tv) + qt * 128 + qw * 64 + qg * 16 + tx) * Dv + h * 64;
            #pragma unroll
            for (int nf = 0; nf < 4; nf++) {
                f4 op = o[qg][nf] +
                    *reinterpret_cast<const f4*>(&ex[((qg * 4 + nf) * 64 + lane) * 4]);
                sh4 ph;
                #pragma unroll
                for (int i = 0; i < 4; i++) ph[i] = (short)bf16_rn(op[i] * inv);
                *reinterpret_cast<sh4*>(&yh[ybase + nf * 16 + g * 4]) = ph;
            }
        }
    }
}

// ---------------------------------------------------------------------------
// Kernel 3: out = y @ Wo^T, fp32 out.  Single bf16 segment, K=1024 (16 steps),
// pipelined 2-buffer, counted vmcnt(6), main loop UNROLLED x2.
// ---------------------------------------------------------------------------
__global__ __launch_bounds__(256) void out_gemm(
    const unsigned short* __restrict__ yh,
    const unsigned short* __restrict__ woh,
    float* __restrict__ out)
{
    __shared__ __align__(16) unsigned short As[2][64 * 64], Bs[2][128 * 64];
    const int tid = threadIdx.x;
    const int lane = tid & 63, w = tid >> 6;
    const int g = lane >> 4, tx = lane & 15;
    const int wr = w >> 1, wc = w & 1;
    const int m0 = blockIdx.x * 64, n0 = blockIdx.y * 128;
    const int srow = lane >> 3, scol = lane & 7;

    f4 acc[2][4] = {};

    auto stage = [&](int buf, int step) {      // 6 gload16 per wave
        int k0 = step * 64;
        #pragma unroll
        for (int c = 0; c < 2; c++) {
            int row = w * 16 + c * 8 + srow;
            int su = (scol ^ (row & 7)) << 3;
            gload16(&yh[(size_t)(m0 + row) * Dv + k0 + su], &As[buf][(w * 16 + c * 8) * 64]);
        }
        #pragma unroll
        for (int c = 0; c < 4; c++) {
            int row = w * 32 + c * 8 + srow;
            int su = (scol ^ (row & 7)) << 3;
            gload16(&woh[(size_t)(n0 + row) * Dv + k0 + su], &Bs[buf][(w * 32 + c * 8) * 64]);
        }
    };
    auto compute = [&](int buf) {
        #pragma unroll
        for (int ks = 0; ks < 2; ks++) {
            sh8 fa[2], fb[4];
            #pragma unroll
            for (int mi = 0; mi < 2; mi++) {
                int r = wr * 32 + mi * 16 + tx;
                fa[mi] = *reinterpret_cast<const sh8*>(
                    &As[buf][(r * 64 + ks * 32 + g * 8) ^ ((r & 7) << 3)]);
            }
            #pragma unroll
            for (int ni = 0; ni < 4; ni++) {
                int r = wc * 64 + ni * 16 + tx;
                fb[ni] = *reinterpret_cast<const sh8*>(
                    &Bs[buf][(r * 64 + ks * 32 + g * 8) ^ ((r & 7) << 3)]);
            }
            #pragma unroll
            for (int mi = 0; mi < 2; mi++)
                #pragma unroll
                for (int ni = 0; ni < 4; ni++)
                    acc[mi][ni] = MFMA(fb[ni], fa[mi], acc[mi][ni]);   // C: row=n, col=m
        }
    };
    auto step = [&](int buf, int t) {
        if (t < 15) asm volatile("s_waitcnt vmcnt(6)" ::: "memory");
        else        asm volatile("s_waitcnt vmcnt(0)" ::: "memory");
        __builtin_amdgcn_s_barrier();
        __builtin_amdgcn_sched_barrier(0);
        compute(buf);
        __builtin_amdgcn_sched_barrier(0);
        __builtin_amdgcn_s_barrier();
        if (t + 2 < 16) stage(buf, t + 2);
    };

    stage(0, 0); stage(1, 1);                  // 12 loads in flight
    #pragma unroll 1
    for (int tt = 0; tt < 16; tt += 2) { step(0, tt); step(1, tt + 1); }

    #pragma unroll
    for (int mi = 0; mi < 2; mi++)
        #pragma unroll
        for (int ni = 0; ni < 4; ni++) {
            int m = m0 + wr * 32 + mi * 16 + tx;
            int n = n0 + wc * 64 + ni * 16 + g * 4;
            *reinterpret_cast<float4*>(&out[(size_t)m * Dv + n]) =
                make_float4(acc[mi][ni][0], acc[mi][ni][1], acc[mi][ni][2], acc[mi][ni][3]);
        }
}

// ---------------------------------------------------------------------------
extern "C" void kernel_launch(void* const* d_in, const int* in_sizes, int n_in,
                              void* d_out, int out_size, void* d_ws, size_t ws_size,
                              hipStream_t stream)
{
    const float* x  = (const float*)d_in[0];
    const float* pk = (const float*)d_in[1];
    const float* pv = (const float*)d_in[2];
    const float* Wq = (const float*)d_in[3];
    const float* Wk = (const float*)d_in[4];
    const float* Wv = (const float*)d_in[5];
    const float* Wo = (const float*)d_in[6];

    const size_t M1 = 1048576;
    unsigned short* ws  = (unsigned short*)d_ws;   // 23M ushorts = 46 MB
    unsigned short* xb   = ws;                     // 4M  [B*T, D]
    unsigned short* wqb  = ws + 4  * M1;           // 1M
    unsigned short* wkb  = ws + 5  * M1;
    unsigned short* wvb  = ws + 6  * M1;
    unsigned short* woh  = ws + 7  * M1;
    unsigned short* pkb  = ws + 8  * M1;           // [B,H,P,DH]
    unsigned short* pvtb = ws + 9  * M1;           // [B,H,DH,P] tau-permuted keys
    unsigned short* qb   = ws + 10 * M1;           // 4M [B,T,D] (pre-scaled by C)
    unsigned short* kb   = ws + 14 * M1;           // 4M [B,T,D]
    unsigned short* vtb  = ws + 18 * M1;           // 4M [B,H,DH,T] tau-permuted keys
    unsigned short* yh   = ws + 22 * M1;           // 4M [B,T,D]

    prep_all<<<9472, 256, 0, stream>>>(x, Wq, Wk, Wv, pk, Wo, pv,
                                       xb, wqb, wkb, wvb, pkb, woh, pvtb);
    qkv_gemm<<<dim3(32, 8, 3), 256, 0, stream>>>(xb, wqb, wkb, wvb, qb, kb, vtb);
    flash_mfma<<<dim3(Bv * Hv * (Tv / 128)), 256, 0, stream>>>(qb, kb, vtb, pkb, pvtb, yh);
    out_gemm<<<dim3(64, 8), 256, 0, stream>>>(yh, woh, (float*)d_out);
}

// Round 16
// 120.581 us; speedup vs baseline: 1.2602x; 1.2602x over previous
//
#include <hip/hip_runtime.h>
#include <cstdint>

#define Bv  2
#define Tv  2048
#define Dv  1024
#define Hv  16
#define DHv 64
#define Pv  512
#define Lv  2560   // P + T
#define NT  (Lv / 64)   // 40 key tiles

typedef __attribute__((ext_vector_type(8))) short sh8;   // 8 bf16 MFMA frag
typedef __attribute__((ext_vector_type(4))) short sh4;
typedef __attribute__((ext_vector_type(4))) float f4;
typedef __attribute__((ext_vector_type(4))) unsigned int u4v;

#define MFMA(a,b,c) __builtin_amdgcn_mfma_f32_16x16x32_bf16(a,b,c,0,0,0)

__device__ __forceinline__ unsigned short bf16_rn(float f) {
    unsigned int u = __builtin_bit_cast(unsigned int, f);
    u += 0x7FFFu + ((u >> 16) & 1u);          // RTNE
    return (unsigned short)(u >> 16);
}
__device__ __forceinline__ float bf16_f(unsigned short h) {
    unsigned int u = ((unsigned int)h) << 16;
    return __builtin_bit_cast(float, u);
}
__device__ __forceinline__ unsigned int fbits(float f) {
    return __builtin_bit_cast(unsigned int, f);
}

// async global->LDS, 16B per lane; LDS dest = wave-uniform base + lane*16
__device__ __forceinline__ void gload16(const unsigned short* g, unsigned short* l) {
    __builtin_amdgcn_global_load_lds(
        (const __attribute__((address_space(1))) unsigned int*)(g),
        (__attribute__((address_space(3))) unsigned int*)(l),
        16, 0, 0);
}

// exp2 + truncate-pack two QK accumulators (8 P values) into one bf16 B-frag.
__device__ __forceinline__ sh8 packP(const f4 a, const f4 b) {
    float e0 = __builtin_amdgcn_exp2f(a[0]), e1 = __builtin_amdgcn_exp2f(a[1]);
    float e2 = __builtin_amdgcn_exp2f(a[2]), e3 = __builtin_amdgcn_exp2f(a[3]);
    float f0 = __builtin_amdgcn_exp2f(b[0]), f1 = __builtin_amdgcn_exp2f(b[1]);
    float f2 = __builtin_amdgcn_exp2f(b[2]), f3 = __builtin_amdgcn_exp2f(b[3]);
    u4v d;
    d[0] = __builtin_amdgcn_perm(fbits(e1), fbits(e0), 0x07060302u);
    d[1] = __builtin_amdgcn_perm(fbits(e3), fbits(e2), 0x07060302u);
    d[2] = __builtin_amdgcn_perm(fbits(f1), fbits(f0), 0x07060302u);
    d[3] = __builtin_amdgcn_perm(fbits(f3), fbits(f2), 0x07060302u);
    return __builtin_bit_cast(sh8, d);
}

// ---------------------------------------------------------------------------
// Prep (merged): blocks [0,9216) = fp32->bf16 conversions (x,Wq,Wk,Wv,pk,Wo);
// blocks [9216,9472) = pv transpose to [B,H,DH,P'] with tau-permuted keys.
// ---------------------------------------------------------------------------
__global__ __launch_bounds__(256) void prep_all(
    const float* __restrict__ x,  const float* __restrict__ Wq,
    const float* __restrict__ Wk, const float* __restrict__ Wv,
    const float* __restrict__ pk, const float* __restrict__ Wo,
    const float* __restrict__ pv,
    unsigned short* __restrict__ xb,  unsigned short* __restrict__ wqb,
    unsigned short* __restrict__ wkb, unsigned short* __restrict__ wvb,
    unsigned short* __restrict__ pkb, unsigned short* __restrict__ woh,
    unsigned short* __restrict__ pvtb)
{
    __shared__ unsigned short Tls[64][66];
    const int blk = blockIdx.x;
    const int tid = threadIdx.x;
    if (blk < 9216) {
        int i = blk * 256 + tid;              // float4 index, total 2359296
        const float* src; unsigned short* dst; int off;
        if      (i < 1048576) { src = x;  dst = xb;  off = i; }
        else if (i < 1310720) { src = Wq; dst = wqb; off = i - 1048576; }
        else if (i < 1572864) { src = Wk; dst = wkb; off = i - 1310720; }
        else if (i < 1835008) { src = Wv; dst = wvb; off = i - 1572864; }
        else if (i < 2097152) { src = pk; dst = pkb; off = i - 1835008; }
        else                  { src = Wo; dst = woh; off = i - 2097152; }
        float4 v = reinterpret_cast<const float4*>(src)[off];
        sh4 h;
        h[0] = (short)bf16_rn(v.x); h[1] = (short)bf16_rn(v.y);
        h[2] = (short)bf16_rn(v.z); h[3] = (short)bf16_rn(v.w);
        reinterpret_cast<sh4*>(dst)[off] = h;
    } else {
        const int bb = blk - 9216;            // 0..255
        const int bh = bb >> 3, pt = bb & 7;
        #pragma unroll
        for (int i = 0; i < 4; i++) {
            int id = i * 256 + tid;
            int p = id >> 4, c4 = (id & 15) << 2;
            float4 v = *reinterpret_cast<const float4*>(
                &pv[((size_t)bh * Pv + pt * 64 + p) * DHv + c4]);
            Tls[c4+0][p] = bf16_rn(v.x);
            Tls[c4+1][p] = bf16_rn(v.y);
            Tls[c4+2][p] = bf16_rn(v.z);
            Tls[c4+3][p] = bf16_rn(v.w);
        }
        __syncthreads();
        #pragma unroll
        for (int i = 0; i < 2; i++) {
            int id = i * 256 + tid;
            int d = id >> 3, u = id & 7;      // dh row, 8-key run index
            sh4 lo, hi;
            #pragma unroll
            for (int j = 0; j < 4; j++) {
                lo[j] = (short)Tls[d][u * 8 + j];
                hi[j] = (short)Tls[d][u * 8 + 4 + j];
            }
            int p0 = ((u >> 2) & 1) * 32 + (u & 1) * 16 + ((u >> 1) & 1) * 4;
            size_t base = ((size_t)bh * DHv + d) * Pv + pt * 64;
            *reinterpret_cast<sh4*>(&pvtb[base + p0])     = lo;
            *reinterpret_cast<sh4*>(&pvtb[base + p0 + 8]) = hi;
        }
    }
}

// ---------------------------------------------------------------------------
// Kernel 1: QKV projection, pipelined (2-buffer, counted vmcnt(8)).
// Q pre-scaled by 0.125*log2(e); V^T stored tau-permuted per 64-tile.
// ---------------------------------------------------------------------------
__global__ __launch_bounds__(256) void qkv_gemm(
    const unsigned short* __restrict__ xb,
    const unsigned short* __restrict__ wqb, const unsigned short* __restrict__ wkb,
    const unsigned short* __restrict__ wvb,
    unsigned short* __restrict__ qb, unsigned short* __restrict__ kb,
    unsigned short* __restrict__ vtb)
{
    __shared__ __align__(16) unsigned short As[2][128 * 64], Bs[2][128 * 64];
    const int tid = threadIdx.x;
    const int lane = tid & 63, w = tid >> 6;
    const int g = lane >> 4, tx = lane & 15;
    const int wr = w >> 1, wc = w & 1;
    const int m0 = blockIdx.x * 128, n0 = blockIdx.y * 128;
    const int z = blockIdx.z;
    const unsigned short* Wb = (z == 0) ? wqb : (z == 1) ? wkb : wvb;
    const int srow = lane >> 3, scol = lane & 7;

    f4 acc[4][4] = {};

    auto stage = [&](int buf, int step) {      // 8 gload16 per wave
        int k0 = step * 64;
        #pragma unroll
        for (int c = 0; c < 4; c++) {
            int row = w * 32 + c * 8 + srow;
            int su = (scol ^ (row & 7)) << 3;
            gload16(&xb[(size_t)(m0 + row) * Dv + k0 + su], &As[buf][(w * 32 + c * 8) * 64]);
            gload16(&Wb[(size_t)(n0 + row) * Dv + k0 + su], &Bs[buf][(w * 32 + c * 8) * 64]);
        }
    };
    auto compute = [&](int buf) {
        #pragma unroll
        for (int ks = 0; ks < 2; ks++) {
            sh8 fa[4], fb[4];
            #pragma unroll
            for (int mi = 0; mi < 4; mi++) {
                int r = wr * 64 + mi * 16 + tx;
                fa[mi] = *reinterpret_cast<const sh8*>(
                    &As[buf][(r * 64 + ks * 32 + g * 8) ^ ((r & 7) << 3)]);
            }
            #pragma unroll
            for (int ni = 0; ni < 4; ni++) {
                int r = wc * 64 + ni * 16 + tx;
                fb[ni] = *reinterpret_cast<const sh8*>(
                    &Bs[buf][(r * 64 + ks * 32 + g * 8) ^ ((r & 7) << 3)]);
            }
            if (z < 2) {
                #pragma unroll
                for (int mi = 0; mi < 4; mi++)
                    #pragma unroll
                    for (int ni = 0; ni < 4; ni++)
                        acc[mi][ni] = MFMA(fb[ni], fa[mi], acc[mi][ni]);   // C: row=n, col=m
            } else {
                #pragma unroll
                for (int mi = 0; mi < 4; mi++)
                    #pragma unroll
                    for (int ni = 0; ni < 4; ni++)
                        acc[mi][ni] = MFMA(fa[mi], fb[ni], acc[mi][ni]);   // C: row=m, col=n
            }
        }
    };

    stage(0, 0); stage(1, 1);                  // 16 loads in flight
    #pragma unroll 1
    for (int t = 0; t < 16; t++) {
        const int cur = t & 1;
        if (t < 15) asm volatile("s_waitcnt vmcnt(8)" ::: "memory");
        else        asm volatile("s_waitcnt vmcnt(0)" ::: "memory");
        __builtin_amdgcn_s_barrier();
        __builtin_amdgcn_sched_barrier(0);
        compute(cur);
        __builtin_amdgcn_sched_barrier(0);
        __builtin_amdgcn_s_barrier();          // all reads of cur done
        if (t + 2 < 16) stage(cur, t + 2);     // overwrite cur for step t+2
    }

    if (z < 2) {
        unsigned short* ob = (z == 0) ? qb : kb;
        const float sc = (z == 0) ? 0.1803368801f : 1.0f;   // 0.125*log2(e) into Q
        #pragma unroll
        for (int mi = 0; mi < 4; mi++)
            #pragma unroll
            for (int ni = 0; ni < 4; ni++) {
                int m = m0 + wr * 64 + mi * 16 + tx;          // col of C = x row
                int n = n0 + wc * 64 + ni * 16 + g * 4;       // row of C = W row (base)
                sh4 pkd;
                #pragma unroll
                for (int i = 0; i < 4; i++) pkd[i] = (short)bf16_rn(acc[mi][ni][i] * sc);
                *reinterpret_cast<sh4*>(&ob[(size_t)m * Dv + n]) = pkd;
            }
    } else {
        const int tb0 = ((m0 + wr * 64) & (Tv - 1));          // 64-aligned t-block
        const int b   = (m0 + wr * 64) >> 11;
        #pragma unroll
        for (int mi = 0; mi < 4; mi++)
            #pragma unroll
            for (int ni = 0; ni < 4; ni++) {
                // key = mi*16 + g*4 + i  ->  tau-slot = 32*(mi>>1) + 8g + 4*(mi&1) + i
                int t = tb0 + ((mi & 2) << 4) + (g << 3) + ((mi & 1) << 2);
                int n = n0 + wc * 64 + ni * 16 + tx;          // col of C = W row
                int h = n >> 6, dh = n & 63;
                sh4 pkd;
                #pragma unroll
                for (int i = 0; i < 4; i++) pkd[i] = (short)bf16_rn(acc[mi][ni][i]);
                *reinterpret_cast<sh4*>(&vtb[(((size_t)(b * Hv + h)) * DHv + dh) * Tv + t]) = pkd;
            }
    }
}

// ---------------------------------------------------------------------------
// Kernel 2: flash attention (round-12/13 best).  KEY-SPLIT + 3-buffer
// single-barrier pipeline, counted vmcnt, tau key-relabel keeps P in
// registers, no-max softmax, l via ones-MFMA.  LDS 50KB, 112 VGPR.
// ---------------------------------------------------------------------------
__global__ __launch_bounds__(256) void flash_mfma(
    const unsigned short* __restrict__ qbuf, const unsigned short* __restrict__ kb,
    const unsigned short* __restrict__ vtb,
    const unsigned short* __restrict__ pkb, const unsigned short* __restrict__ pvtb,
    unsigned short* __restrict__ yh)
{
    __shared__ __align__(16) unsigned short Ks[3][64 * 64], Vs[3][64 * 64];
    __shared__ float olex[2][4][64];
    const int tid = threadIdx.x;
    const int lane = tid & 63, w = tid >> 6;       // 4 waves
    const int kw = w & 1, qw = w >> 1;             // key-half, q-half
    const int g = lane >> 4, tx = lane & 15;
    // XCD swizzle: 512 blocks, 8 XCDs, chunk=64 => 4 bh per XCD
    const int pblk = blockIdx.x;
    const int L = (pblk & 7) * 64 + (pblk >> 3);
    const int qt = L & 15;                 // 16 q-tiles of 128 rows
    const int bh = L >> 4;
    const int b = bh >> 4, h = bh & 15;
    const int srow = lane >> 3, scol = lane & 7;

    // Q frags: 4 groups x 2 dh-halves (MFMA B-operand, pre-scaled)
    sh8 qf[4][2];
    #pragma unroll
    for (int qg = 0; qg < 4; qg++) {
        size_t base = ((size_t)(b * Tv) + qt * 128 + qw * 64 + qg * 16 + tx) * Dv + h * 64;
        qf[qg][0] = *reinterpret_cast<const sh8*>(&qbuf[base + g * 8]);
        qf[qg][1] = *reinterpret_cast<const sh8*>(&qbuf[base + 32 + g * 8]);
    }

    f4 o[4][4] = {};          // [q-group][dh-frag], partial over this wave's keys
    f4 ol[4] = {};            // ones-colsum accumulators (partial l per group)
    sh8 onesf;
    #pragma unroll
    for (int j = 0; j < 8; j++) onesf[j] = (short)0x3F80;   // bf16 1.0

    // staging pointers (wave stages rows w*16..+15 of both K and V tiles)
    const int r0 = w * 16 + srow, r1 = r0 + 8;
    const int su0 = (scol ^ (r0 & 7)) << 3;
    const int su1 = (scol ^ (r1 & 7)) << 3;
    const unsigned short* ka0 = &pkb[((size_t)bh * Pv + r0) * DHv + su0];
    const unsigned short* ka1 = &pkb[((size_t)bh * Pv + r1) * DHv + su1];
    const unsigned short* va0 = &pvtb[((size_t)bh * DHv + r0) * Pv + su0];
    const unsigned short* va1 = &pvtb[((size_t)bh * DHv + r1) * Pv + su1];

    auto stage = [&](int buf) {            // 4 gload16 per wave per tile
        gload16(ka0, &Ks[buf][(w * 16    ) * 64]);
        gload16(ka1, &Ks[buf][(w * 16 + 8) * 64]);
        gload16(va0, &Vs[buf][(w * 16    ) * 64]);
        gload16(va1, &Vs[buf][(w * 16 + 8) * 64]);
    };
    auto advance = [&](int nt) {           // nt = tile just staged
        if (nt == 7) {                     // switch prefix -> computed arrays
            ka0 = &kb[((size_t)(b * Tv) + r0) * Dv + h * 64 + su0];
            ka1 = &kb[((size_t)(b * Tv) + r1) * Dv + h * 64 + su1];
            va0 = &vtb[((size_t)bh * DHv + r0) * Tv + su0];
            va1 = &vtb[((size_t)bh * DHv + r1) * Tv + su1];
        } else if (nt < 7) { ka0 += 64 * DHv; ka1 += 64 * DHv; va0 += 64; va1 += 64; }
        else               { ka0 += 64 * Dv;  ka1 += 64 * Dv;  va0 += 64; va1 += 64; }
    };

    auto compute = [&](int cur) {
        sh8 kf[2][2], vf[4];
        #pragma unroll
        for (int nf = 0; nf < 2; nf++) {
            int rk = 32 * kw + nf * 16 + tx;
            kf[nf][0] = *reinterpret_cast<const sh8*>(
                &Ks[cur][(rk * 64 + g * 8) ^ ((rk & 7) << 3)]);
            kf[nf][1] = *reinterpret_cast<const sh8*>(
                &Ks[cur][(rk * 64 + 32 + g * 8) ^ ((rk & 7) << 3)]);
        }
        #pragma unroll
        for (int nf = 0; nf < 4; nf++) {
            int rv = nf * 16 + tx;
            vf[nf] = *reinterpret_cast<const sh8*>(
                &Vs[cur][(rv * 64 + 32 * kw + g * 8) ^ ((rv & 7) << 3)]);
        }
        #pragma unroll
        for (int qg = 0; qg < 4; qg++) {
            f4 sa = {}, sb = {};
            sa = MFMA(kf[0][0], qf[qg][0], sa); sa = MFMA(kf[0][1], qf[qg][1], sa);
            sb = MFMA(kf[1][0], qf[qg][0], sb); sb = MFMA(kf[1][1], qf[qg][1], sb);
            sh8 pf = packP(sa, sb);            // tau-slots 32kw + 8g + 4nf' + i
            #pragma unroll
            for (int nf = 0; nf < 4; nf++)
                o[qg][nf] = MFMA(vf[nf], pf, o[qg][nf]);
            ol[qg] = MFMA(onesf, pf, ol[qg]);
        }
    };

    stage(0); advance(0);
    stage(1); advance(1);                  // 8 loads in flight
    int cur = 0, stg = 2;

    #pragma unroll 1
    for (int t = 0; t < NT - 2; t++) {
        asm volatile("s_waitcnt vmcnt(4)" ::: "memory");   // tile t landed; t+1 flying
        __builtin_amdgcn_s_barrier();
        __builtin_amdgcn_sched_barrier(0);
        stage(stg); advance(t + 2);        // overwrite target: computed at t-1, safe
        compute(cur);
        __builtin_amdgcn_sched_barrier(0);
        cur = (cur == 2) ? 0 : cur + 1;
        stg = (stg == 2) ? 0 : stg + 1;
    }
    asm volatile("s_waitcnt vmcnt(4)" ::: "memory");       // tile NT-2 landed
    __builtin_amdgcn_s_barrier();
    __builtin_amdgcn_sched_barrier(0);
    compute(cur);
    __builtin_amdgcn_sched_barrier(0);
    cur = (cur == 2) ? 0 : cur + 1;
    asm volatile("s_waitcnt vmcnt(0)" ::: "memory");       // tile NT-1 landed
    __builtin_amdgcn_s_barrier();
    __builtin_amdgcn_sched_barrier(0);
    compute(cur);

    // cross-wave (kw) reduction: kw=1 writes partials to dead Ks/Vs, kw=0 adds
    float* ex = qw ? reinterpret_cast<float*>(Vs) : reinterpret_cast<float*>(Ks);
    if (kw) {
        #pragma unroll
        for (int qg = 0; qg < 4; qg++) {
            #pragma unroll
            for (int nf = 0; nf < 4; nf++)
                *reinterpret_cast<f4*>(&ex[((qg * 4 + nf) * 64 + lane) * 4]) = o[qg][nf];
            olex[qw][qg][lane] = ol[qg][0];
        }
    }
    __syncthreads();
    if (!kw) {
        #pragma unroll
        for (int qg = 0; qg < 4; qg++) {
            float l = ol[qg][0] + olex[qw][qg][lane];
            float inv = 1.0f / l;
            size_t ybase = ((size_t)(b * Tv) + qt * 128 + qw * 64 + qg * 16 + tx) * Dv + h * 64;
            #pragma unroll
            for (int nf = 0; nf < 4; nf++) {
                f4 op = o[qg][nf] +
                    *reinterpret_cast<const f4*>(&ex[((qg * 4 + nf) * 64 + lane) * 4]);
                sh4 ph;
                #pragma unroll
                for (int i = 0; i < 4; i++) ph[i] = (short)bf16_rn(op[i] * inv);
                *reinterpret_cast<sh4*>(&yh[ybase + nf * 16 + g * 4]) = ph;
            }
        }
    }
}

// ---------------------------------------------------------------------------
// Kernel 3: out = y @ Wo^T, fp32 out.  Single bf16 segment, K=1024 (16 steps),
// pipelined 2-buffer, counted vmcnt(6).
// ---------------------------------------------------------------------------
__global__ __launch_bounds__(256) void out_gemm(
    const unsigned short* __restrict__ yh,
    const unsigned short* __restrict__ woh,
    float* __restrict__ out)
{
    __shared__ __align__(16) unsigned short As[2][64 * 64], Bs[2][128 * 64];
    const int tid = threadIdx.x;
    const int lane = tid & 63, w = tid >> 6;
    const int g = lane >> 4, tx = lane & 15;
    const int wr = w >> 1, wc = w & 1;
    const int m0 = blockIdx.x * 64, n0 = blockIdx.y * 128;
    const int srow = lane >> 3, scol = lane & 7;

    f4 acc[2][4] = {};

    auto stage = [&](int buf, int step) {      // 6 gload16 per wave
        int k0 = step * 64;
        #pragma unroll
        for (int c = 0; c < 2; c++) {
            int row = w * 16 + c * 8 + srow;
            int su = (scol ^ (row & 7)) << 3;
            gload16(&yh[(size_t)(m0 + row) * Dv + k0 + su], &As[buf][(w * 16 + c * 8) * 64]);
        }
        #pragma unroll
        for (int c = 0; c < 4; c++) {
            int row = w * 32 + c * 8 + srow;
            int su = (scol ^ (row & 7)) << 3;
            gload16(&woh[(size_t)(n0 + row) * Dv + k0 + su], &Bs[buf][(w * 32 + c * 8) * 64]);
        }
    };
    auto compute = [&](int buf) {
        #pragma unroll
        for (int ks = 0; ks < 2; ks++) {
            sh8 fa[2], fb[4];
            #pragma unroll
            for (int mi = 0; mi < 2; mi++) {
                int r = wr * 32 + mi * 16 + tx;
                fa[mi] = *reinterpret_cast<const sh8*>(
                    &As[buf][(r * 64 + ks * 32 + g * 8) ^ ((r & 7) << 3)]);
            }
            #pragma unroll
            for (int ni = 0; ni < 4; ni++) {
                int r = wc * 64 + ni * 16 + tx;
                fb[ni] = *reinterpret_cast<const sh8*>(
                    &Bs[buf][(r * 64 + ks * 32 + g * 8) ^ ((r & 7) << 3)]);
            }
            #pragma unroll
            for (int mi = 0; mi < 2; mi++)
                #pragma unroll
                for (int ni = 0; ni < 4; ni++)
                    acc[mi][ni] = MFMA(fb[ni], fa[mi], acc[mi][ni]);   // C: row=n, col=m
        }
    };

    stage(0, 0); stage(1, 1);                  // 12 loads in flight
    #pragma unroll 1
    for (int t = 0; t < 16; t++) {
        const int cur = t & 1;
        if (t < 15) asm volatile("s_waitcnt vmcnt(6)" ::: "memory");
        else        asm volatile("s_waitcnt vmcnt(0)" ::: "memory");
        __builtin_amdgcn_s_barrier();
        __builtin_amdgcn_sched_barrier(0);
        compute(cur);
        __builtin_amdgcn_sched_barrier(0);
        __builtin_amdgcn_s_barrier();
        if (t + 2 < 16) stage(cur, t + 2);
    }

    #pragma unroll
    for (int mi = 0; mi < 2; mi++)
        #pragma unroll
        for (int ni = 0; ni < 4; ni++) {
            int m = m0 + wr * 32 + mi * 16 + tx;
            int n = n0 + wc * 64 + ni * 16 + g * 4;
            *reinterpret_cast<float4*>(&out[(size_t)m * Dv + n]) =
                make_float4(acc[mi][ni][0], acc[mi][ni][1], acc[mi][ni][2], acc[mi][ni][3]);
        }
}

// ---------------------------------------------------------------------------
extern "C" void kernel_launch(void* const* d_in, const int* in_sizes, int n_in,
                              void* d_out, int out_size, void* d_ws, size_t ws_size,
                              hipStream_t stream)
{
    const float* x  = (const float*)d_in[0];
    const float* pk = (const float*)d_in[1];
    const float* pv = (const float*)d_in[2];
    const float* Wq = (const float*)d_in[3];
    const float* Wk = (const float*)d_in[4];
    const float* Wv = (const float*)d_in[5];
    const float* Wo = (const float*)d_in[6];

    const size_t M1 = 1048576;
    unsigned short* ws  = (unsigned short*)d_ws;   // 23M ushorts = 46 MB
    unsigned short* xb   = ws;                     // 4M  [B*T, D]
    unsigned short* wqb  = ws + 4  * M1;           // 1M
    unsigned short* wkb  = ws + 5  * M1;
    unsigned short* wvb  = ws + 6  * M1;
    unsigned short* woh  = ws + 7  * M1;
    unsigned short* pkb  = ws + 8  * M1;           // [B,H,P,DH]
    unsigned short* pvtb = ws + 9  * M1;           // [B,H,DH,P] tau-permuted keys
    unsigned short* qb   = ws + 10 * M1;           // 4M [B,T,D] (pre-scaled by C)
    unsigned short* kb   = ws + 14 * M1;           // 4M [B,T,D]
    unsigned short* vtb  = ws + 18 * M1;           // 4M [B,H,DH,T] tau-permuted keys
    unsigned short* yh   = ws + 22 * M1;           // 4M [B,T,D]

    prep_all<<<9472, 256, 0, stream>>>(x, Wq, Wk, Wv, pk, Wo, pv,
                                       xb, wqb, wkb, wvb, pkb, woh, pvtb);
    qkv_gemm<<<dim3(32, 8, 3), 256, 0, stream>>>(xb, wqb, wkb, wvb, qb, kb, vtb);
    flash_mfma<<<dim3(Bv * Hv * (Tv / 128)), 256, 0, stream>>>(qb, kb, vtb, pkb, pvtb, yh);
    out_gemm<<<dim3(64, 8), 256, 0, stream>>>(yh, woh, (float*)d_out);
}